// Round 2
// 1625.072 us; speedup vs baseline: 1.1659x; 1.1659x over previous
//
#include <hip/hip_runtime.h>
#include <cstddef>

#define T_DIM 1024
#define S_DIM 1024
#define B_DIM 8
#define E_DIM 1024
#define H_DIM 16
#define D_DIM 64
#define NBHTD (B_DIM*H_DIM*T_DIM*D_DIM)   // 8388608 elements per [B,H,T,D] tensor

typedef __attribute__((ext_vector_type(8))) short short8;
typedef __attribute__((ext_vector_type(4))) short short4v;
typedef __attribute__((ext_vector_type(4))) float floatx4;

// ---- bf16 helpers (RNE via bit ops; no NaN inputs here) ----
__device__ inline unsigned short f2bf(float x){
    union { float f; unsigned u; } v; v.f = x;
    unsigned r = (v.u + 0x7FFFu + ((v.u >> 16) & 1u)) >> 16;
    return (unsigned short)r;
}
__device__ inline float bf2f(unsigned short h){
    union { float f; unsigned u; } v; v.u = ((unsigned)h) << 16; return v.f;
}

// async global->LDS, 16B per lane
typedef __attribute__((address_space(1))) const unsigned int* gptr_t;
typedef __attribute__((address_space(3))) unsigned int* lptr_t;
__device__ inline void gl_lds16(const void* g, void* l){
    __builtin_amdgcn_global_load_lds((gptr_t)g, (lptr_t)l, 16, 0, 0);
}

// swizzled offset into the 16x1024 bf16 prob buffer (u16 index).
// 8-u16 (16B) chunks XOR'd by row&7 -> ds_read_b128 / ds_write_b64 land on
// distinct bank groups across the 16 rows (>=8-way spread, ~2-way residual).
__device__ inline int poff(int row, int s){
    return (row << 10) + ((((s >> 3) ^ (row & 7)) << 3)) + (s & 7);
}

// ---------------------------------------------------------------------------
// Element-wise bf16 hi/lo split (optionally scaled): x -> hi=bf16(x),
// lo=bf16(x-hi).  8 elems/thread.
// ---------------------------------------------------------------------------
__global__ __launch_bounds__(256)
void split_pair(const float* __restrict__ src, unsigned short* __restrict__ hi,
                unsigned short* __restrict__ lo, float scale)
{
    size_t i = ((size_t)blockIdx.x*256 + threadIdx.x)*8;
    float4 a = *(const float4*)(src+i);
    float4 b = *(const float4*)(src+i+4);
    float v[8] = {a.x,a.y,a.z,a.w,b.x,b.y,b.z,b.w};
    short8 h8, l8;
    #pragma unroll
    for (int j = 0; j < 8; ++j) {
        float x = v[j]*scale;
        unsigned short hh = f2bf(x);
        h8[j] = (short)hh;
        l8[j] = (short)f2bf(x - bf2f(hh));
    }
    *(short8*)(hi+i) = h8;
    *(short8*)(lo+i) = l8;
}

// ---------------------------------------------------------------------------
// bf16x3 MFMA GEMM: C[m,n] = sum_k A[m,k]*B[n,k], M=8192, N=K=1024.
// A,B pre-split bf16 hi/lo.  acc += Ah*Bh + Ah*Bl + Al*Bh  (rel err ~2^-17).
// AMODE 0: A row-major [8192,1024]. AMODE 1: A gathered from [B,H,T,D]
//   (row r = t*8+b, col e = h*64+d).
// CMODE 0: Cf fp32 scatter to [B,H,T,D].  CMODE 1: split bf16 hi/lo scatter
//   to [B,H,T,D].  CMODE 2: Cf fp32 row-major [8192,1024].
// 128x128 tile, BK=32, block 256 (4 waves, 2x2), grid (8, 64).
// ---------------------------------------------------------------------------
template <int AMODE, int CMODE>
__global__ __launch_bounds__(256, 2)
void gemm_bf3(const unsigned short* __restrict__ Ahi, const unsigned short* __restrict__ Alo,
              const unsigned short* __restrict__ Bhi, const unsigned short* __restrict__ Blo,
              float* __restrict__ Cf,
              unsigned short* __restrict__ Chi, unsigned short* __restrict__ Clo)
{
    __shared__ __align__(16) unsigned short lds[4][128*32];  // Ahi,Alo,Bhi,Blo 8KB each

    const int tid  = threadIdx.x;
    const int n0   = blockIdx.x * 128;
    const int m0   = blockIdx.y * 128;
    const int wave = tid >> 6, lane = tid & 63;
    const int lrow = lane & 15, quad = lane >> 4;
    const int mw = (wave & 1)*64, nw = (wave >> 1)*64;

    floatx4 acc[4][4];
    #pragma unroll
    for (int i = 0; i < 4; ++i)
        #pragma unroll
        for (int j = 0; j < 4; ++j) acc[i][j] = (floatx4){0.f,0.f,0.f,0.f};

    for (int kk = 0; kk < 1024; kk += 32) {
        __syncthreads();
        #pragma unroll
        for (int rnd = 0; rnd < 2; ++rnd) {
            int c = rnd*256 + tid;
            int row = c >> 2, col8 = (c & 3)*8;
            size_t aoff;
            if (AMODE == 0) {
                aoff = (size_t)(m0+row)*1024 + kk + col8;
            } else {
                int r = m0 + row; int t = r >> 3, bb = r & 7;
                int h = kk >> 6, d0 = (kk & 63) + col8;
                aoff = (((size_t)(bb*H_DIM + h)*T_DIM) + t)*D_DIM + d0;
            }
            size_t boff = (size_t)(n0+row)*1024 + kk + col8;
            gl_lds16(Ahi + aoff, &lds[0][c*8]);
            gl_lds16(Alo + aoff, &lds[1][c*8]);
            gl_lds16(Bhi + boff, &lds[2][c*8]);
            gl_lds16(Blo + boff, &lds[3][c*8]);
        }
        __syncthreads();

        short8 ah[4], al[4], bh[4], bl[4];
        #pragma unroll
        for (int mt = 0; mt < 4; ++mt) {
            int r = mw + mt*16 + lrow;
            ah[mt] = *(const short8*)&lds[0][r*32 + quad*8];
            al[mt] = *(const short8*)&lds[1][r*32 + quad*8];
        }
        #pragma unroll
        for (int nt = 0; nt < 4; ++nt) {
            int r = nw + nt*16 + lrow;
            bh[nt] = *(const short8*)&lds[2][r*32 + quad*8];
            bl[nt] = *(const short8*)&lds[3][r*32 + quad*8];
        }
        #pragma unroll
        for (int mt = 0; mt < 4; ++mt)
            #pragma unroll
            for (int nt = 0; nt < 4; ++nt) {
                acc[mt][nt] = __builtin_amdgcn_mfma_f32_16x16x32_bf16(ah[mt], bh[nt], acc[mt][nt], 0,0,0);
                acc[mt][nt] = __builtin_amdgcn_mfma_f32_16x16x32_bf16(ah[mt], bl[nt], acc[mt][nt], 0,0,0);
                acc[mt][nt] = __builtin_amdgcn_mfma_f32_16x16x32_bf16(al[mt], bh[nt], acc[mt][nt], 0,0,0);
            }
    }

    // epilogue: C row m = quad*4+r within tile, col n = lrow within tile
    #pragma unroll
    for (int mt = 0; mt < 4; ++mt) {
        #pragma unroll
        for (int nt = 0; nt < 4; ++nt) {
            int n = n0 + nw + nt*16 + lrow;
            #pragma unroll
            for (int r = 0; r < 4; ++r) {
                int m = m0 + mw + mt*16 + quad*4 + r;
                float v = acc[mt][nt][r];
                if (CMODE == 2) {
                    Cf[(size_t)m*1024 + n] = v;
                } else {
                    int t = m >> 3, bb = m & 7;
                    int h = n >> 6, d = n & 63;
                    size_t idx = (((size_t)(bb*H_DIM + h)*T_DIM) + t)*D_DIM + d;
                    if (CMODE == 0) {
                        Cf[idx] = v;
                    } else {
                        unsigned short hh = f2bf(v);
                        Chi[idx] = hh;
                        Clo[idx] = f2bf(v - bf2f(hh));
                    }
                }
            }
        }
    }
}

// ---------------------------------------------------------------------------
// Split+transpose V: fp32 [B,H,S,D] -> bf16 hi/lo [B,H,D,S].
// grid (16, 128), block 256.
// ---------------------------------------------------------------------------
__global__ __launch_bounds__(256)
void split_vt(const float* __restrict__ Vh, unsigned short* __restrict__ Vthi,
              unsigned short* __restrict__ Vtlo)
{
    __shared__ float tile[64][68];
    const int bh = blockIdx.y, s0 = blockIdx.x*64;
    const int tid = threadIdx.x;
    const size_t base = (size_t)bh*S_DIM*D_DIM;

    {
        int r = tid >> 2, c0 = (tid & 3) * 16;
        const float* p = Vh + base + (size_t)(s0 + r)*D_DIM + c0;
        float4 a = *(const float4*)p;
        float4 b = *(const float4*)(p+4);
        float4 c = *(const float4*)(p+8);
        float4 d = *(const float4*)(p+12);
        *(float4*)&tile[r][c0]    = a;
        *(float4*)&tile[r][c0+4]  = b;
        *(float4*)&tile[r][c0+8]  = c;
        *(float4*)&tile[r][c0+12] = d;
    }
    __syncthreads();
    {
        int d = tid >> 2, cs = (tid & 3) * 16;
        short8 hi[2], lo[2];
        #pragma unroll
        for (int half = 0; half < 2; ++half)
            #pragma unroll
            for (int u = 0; u < 8; ++u) {
                float x = tile[cs + half*8 + u][d];
                unsigned short hh = f2bf(x);
                hi[half][u] = (short)hh;
                lo[half][u] = (short)f2bf(x - bf2f(hh));
            }
        size_t obase = base + (size_t)d*S_DIM + s0 + cs;
        *(short8*)(Vthi + obase)     = hi[0];
        *(short8*)(Vthi + obase + 8) = hi[1];
        *(short8*)(Vtlo + obase)     = lo[0];
        *(short8*)(Vtlo + obase + 8) = lo[1];
    }
}

// ---------------------------------------------------------------------------
// MFMA attention pass (one stream), register-resident softmax.
//
// Swapped-operand scores: mfma(K, Q) puts score[s][t] with t = lane&15,
// s = wave*256 + jt*16 + quad*4 + r -> each lane holds the FULL score row
// for one t in 64 VGPRs.  Softmax = in-register trees + 2 quad-shuffles +
// a 512B LDS stats exchange.  Probs converted to bf16 ONCE, stored to a
// 32KB swizzled LDS buffer consumed directly as the PV A-operand.
// 2 barriers/head (was 3), LDS 33KB (was 64KB), zero f32 score traffic.
//
// grid 512 (flat; b = bid&7 pins each batch to one XCD so per-head K/V
// (512KB) stays L2-resident), block 256, LDS 33KB.
// ---------------------------------------------------------------------------
__global__ __launch_bounds__(256, 2)
void attn_mfma(const float* __restrict__ Qh,
               const unsigned short* __restrict__ Khi, const unsigned short* __restrict__ Klo,
               const unsigned short* __restrict__ Vthi, const unsigned short* __restrict__ Vtlo,
               float* __restrict__ Ofp,
               unsigned short* __restrict__ Ohi, unsigned short* __restrict__ Olo,
               float* __restrict__ attn_mean)
{
    const int bid = blockIdx.x;
    const int b   = bid & 7;            // XCD-pinned batch
    const int t0  = (bid >> 3) * 16;
    const int tid  = threadIdx.x;
    const int lane = tid & 63;
    const int wave = tid >> 6;
    const int lrow = lane & 15;
    const int quad = lane >> 4;
    const int t_g  = t0 + lrow;

    __shared__ __align__(16) unsigned short plds[16*1024];  // probs bf16, swizzled
    __shared__ float2 stats[4][16];                          // per-wave (max, sumexp)

    float accm[64];
    #pragma unroll
    for (int i = 0; i < 64; ++i) accm[i] = 0.f;

    #pragma unroll 1
    for (int h = 0; h < H_DIM; ++h) {
        const int bh = b*H_DIM + h;
        const size_t kbase = (size_t)bh * S_DIM * D_DIM;

        // ---- Q fragments (B-operand layout), bf16 hi/lo, k0 = 0 and 32 ----
        short8 qh0, ql0, qh1, ql1;
        {
            const float* qp = Qh + kbase + (size_t)(t0 + lrow)*D_DIM + quad*8;
            float4 a  = *(const float4*)qp;
            float4 b4 = *(const float4*)(qp+4);
            float4 c4 = *(const float4*)(qp+32);
            float4 d4 = *(const float4*)(qp+36);
            float va[8]  = {a.x,a.y,a.z,a.w,b4.x,b4.y,b4.z,b4.w};
            float vb8[8] = {c4.x,c4.y,c4.z,c4.w,d4.x,d4.y,d4.z,d4.w};
            #pragma unroll
            for (int j = 0; j < 8; ++j) {
                unsigned short h0 = f2bf(va[j]);
                qh0[j] = (short)h0; ql0[j] = (short)f2bf(va[j] - bf2f(h0));
                unsigned short h1 = f2bf(vb8[j]);
                qh1[j] = (short)h1; ql1[j] = (short)f2bf(vb8[j] - bf2f(h1));
            }
        }

        // ---- scores (swapped): lane holds s = wave*256+jt*16+quad*4+r for t=t_g.
        //      2-stage software pipeline on the K loads.
        float sv[64];
        {
            const unsigned short* kph = Khi + kbase + (size_t)(wave*256 + lrow)*D_DIM + quad*8;
            const unsigned short* kpl = Klo + kbase + (size_t)(wave*256 + lrow)*D_DIM + quad*8;
            short8 kh0 = *(const short8*)(kph);
            short8 kh1 = *(const short8*)(kph + 32);
            short8 kl0 = *(const short8*)(kpl);
            short8 kl1 = *(const short8*)(kpl + 32);
            #pragma unroll
            for (int jt = 0; jt < 16; ++jt) {
                short8 nh0, nh1, nl0, nl1;
                if (jt < 15) {
                    const unsigned short* nph = kph + (jt+1)*16*D_DIM;
                    const unsigned short* npl = kpl + (jt+1)*16*D_DIM;
                    nh0 = *(const short8*)(nph);
                    nh1 = *(const short8*)(nph + 32);
                    nl0 = *(const short8*)(npl);
                    nl1 = *(const short8*)(npl + 32);
                }
                floatx4 acc = {0.f,0.f,0.f,0.f};
                acc = __builtin_amdgcn_mfma_f32_16x16x32_bf16(kh0, qh0, acc, 0,0,0);
                acc = __builtin_amdgcn_mfma_f32_16x16x32_bf16(kh1, qh1, acc, 0,0,0);
                acc = __builtin_amdgcn_mfma_f32_16x16x32_bf16(kl0, qh0, acc, 0,0,0);
                acc = __builtin_amdgcn_mfma_f32_16x16x32_bf16(kl1, qh1, acc, 0,0,0);
                acc = __builtin_amdgcn_mfma_f32_16x16x32_bf16(kh0, ql0, acc, 0,0,0);
                acc = __builtin_amdgcn_mfma_f32_16x16x32_bf16(kh1, ql1, acc, 0,0,0);
                const int sb = wave*256 + jt*16 + quad*4;
                #pragma unroll
                for (int r = 0; r < 4; ++r)
                    sv[jt*4+r] = (sb + r > t_g) ? 1e-30f : acc[r];
                kh0 = nh0; kh1 = nh1; kl0 = nl0; kl1 = nl1;
            }
        }

        // ---- wave-local max (tree + quad shuffle) ----
        float mt[32];
        #pragma unroll
        for (int i = 0; i < 32; ++i) mt[i] = fmaxf(sv[i], sv[i+32]);
        #pragma unroll
        for (int st = 16; st > 0; st >>= 1) {
            #pragma unroll
            for (int i = 0; i < st; ++i) mt[i] = fmaxf(mt[i], mt[i+st]);
        }
        float m_loc = fmaxf(mt[0], __shfl_xor(mt[0], 16));
        m_loc = fmaxf(m_loc, __shfl_xor(m_loc, 32));

        // ---- exp + wave-local sum ----
        #pragma unroll
        for (int i = 0; i < 64; ++i) sv[i] = __expf(sv[i] - m_loc);
        float st2[32];
        #pragma unroll
        for (int i = 0; i < 32; ++i) st2[i] = sv[i] + sv[i+32];
        #pragma unroll
        for (int st = 16; st > 0; st >>= 1) {
            #pragma unroll
            for (int i = 0; i < st; ++i) st2[i] += st2[i+st];
        }
        float s_loc = st2[0] + __shfl_xor(st2[0], 16);
        s_loc += __shfl_xor(s_loc, 32);

        if (quad == 0) stats[wave][lrow] = make_float2(m_loc, s_loc);
        __syncthreads();   // A: stats ready; prev-head PV reads done

        // ---- global stats combine ----
        float2 c0 = stats[0][lrow], c1 = stats[1][lrow];
        float2 c2 = stats[2][lrow], c3 = stats[3][lrow];
        float m_g = fmaxf(fmaxf(c0.x, c1.x), fmaxf(c2.x, c3.x));
        float sum_g = c0.y*__expf(c0.x - m_g) + c1.y*__expf(c1.x - m_g)
                    + c2.y*__expf(c2.x - m_g) + c3.y*__expf(c3.x - m_g);
        const float myscale = __expf(m_loc - m_g) / sum_g;

        // ---- probs: scale, head-mean accumulate, bf16 -> swizzled LDS ----
        #pragma unroll
        for (int jt = 0; jt < 16; ++jt) {
            float p0 = sv[jt*4+0]*myscale, p1 = sv[jt*4+1]*myscale;
            float p2 = sv[jt*4+2]*myscale, p3 = sv[jt*4+3]*myscale;
            accm[jt*4+0] += p0; accm[jt*4+1] += p1;
            accm[jt*4+2] += p2; accm[jt*4+3] += p3;
            short4v pk;
            pk[0] = (short)f2bf(p0); pk[1] = (short)f2bf(p1);
            pk[2] = (short)f2bf(p2); pk[3] = (short)f2bf(p3);
            const int sidx = wave*256 + jt*16 + quad*4;
            *(short4v*)&plds[poff(lrow, sidx)] = pk;
        }
        __syncthreads();   // B: probs ready

        // ---- PV: wave w owns d-block [16w,16w+16) ----
        {
            const int d0 = wave*16;
            const unsigned short* vh = Vthi + kbase + (size_t)(d0 + lrow)*S_DIM;
            const unsigned short* vl = Vtlo + kbase + (size_t)(d0 + lrow)*S_DIM;
            floatx4 oa = {0.f,0.f,0.f,0.f}, ob = {0.f,0.f,0.f,0.f};
            #pragma unroll 4
            for (int sk = 0; sk < S_DIM; sk += 32) {
                const int sa = sk + quad*8;
                short8 af  = *(const short8*)&plds[poff(lrow, sa)];
                short8 bh8 = *(const short8*)(vh + sa);
                short8 bl8 = *(const short8*)(vl + sa);
                oa = __builtin_amdgcn_mfma_f32_16x16x32_bf16(af, bh8, oa, 0,0,0);
                ob = __builtin_amdgcn_mfma_f32_16x16x32_bf16(af, bl8, ob, 0,0,0);
            }
            #pragma unroll
            for (int r = 0; r < 4; ++r) {
                int q = quad*4 + r;
                float v = oa[r] + ob[r];
                size_t idx = kbase + (size_t)(t0+q)*D_DIM + d0 + lrow;
                if (Ofp) Ofp[idx] = v;
                unsigned short hh = f2bf(v);
                Ohi[idx] = hh;
                Olo[idx] = f2bf(v - bf2f(hh));
            }
        }
    }

    // ---- head-mean write: [B,T,S], lane covers s = wave*256 + jt*16 + quad*4 ----
    {
        float* am = attn_mean + ((size_t)b*T_DIM + t_g)*S_DIM + wave*256 + quad*4;
        #pragma unroll
        for (int jt = 0; jt < 16; ++jt) {
            float4 p4;
            p4.x = accm[jt*4+0]*(1.0f/H_DIM);
            p4.y = accm[jt*4+1]*(1.0f/H_DIM);
            p4.z = accm[jt*4+2]*(1.0f/H_DIM);
            p4.w = accm[jt*4+3]*(1.0f/H_DIM);
            *(float4*)(am + jt*16) = p4;
        }
    }
}

// ---------------------------------------------------------------------------
// k2 = (khi+klo) + o_s, re-split in place.  grid 4096, block 256.
// ---------------------------------------------------------------------------
__global__ __launch_bounds__(256)
void add_k(unsigned short* __restrict__ Khi, unsigned short* __restrict__ Klo,
           const float* __restrict__ O)
{
    size_t i = ((size_t)blockIdx.x*256 + threadIdx.x)*8;
    short8 hi = *(short8*)(Khi+i), lo = *(short8*)(Klo+i);
    float4 o0 = *(const float4*)(O+i), o1 = *(const float4*)(O+i+4);
    float ov[8] = {o0.x,o0.y,o0.z,o0.w,o1.x,o1.y,o1.z,o1.w};
    short8 nh, nl;
    #pragma unroll
    for (int j = 0; j < 8; ++j) {
        float k = bf2f((unsigned short)hi[j]) + bf2f((unsigned short)lo[j]) + ov[j];
        unsigned short hh = f2bf(k);
        nh[j] = (short)hh;
        nl[j] = (short)f2bf(k - bf2f(hh));
    }
    *(short8*)(Khi+i) = nh;
    *(short8*)(Klo+i) = nl;
}

// v2 = v + o_s (fp32 in place).  grid 8192, block 256.
__global__ __launch_bounds__(256)
void add_v(float* __restrict__ V, const float* __restrict__ O)
{
    size_t i = ((size_t)blockIdx.x*256 + threadIdx.x)*4;
    float4 o = *(const float4*)(O+i);
    float4 v = *(const float4*)(V+i);
    v.x+=o.x; v.y+=o.y; v.z+=o.z; v.w+=o.w;
    *(float4*)(V+i) = v;
}

// ---------------------------------------------------------------------------
extern "C" void kernel_launch(void* const* d_in, const int* in_sizes, int n_in,
                              void* d_out, int out_size, void* d_ws, size_t ws_size,
                              hipStream_t stream)
{
    const float* q1  = (const float*)d_in[0];
    const float* q2  = (const float*)d_in[1];
    const float* key = (const float*)d_in[2];
    const float* val = (const float*)d_in[3];
    // d_in[4] = attn_mask (causal triu k=1) computed analytically (s > t)
    const float* qw  = (const float*)d_in[5];
    const float* kw  = (const float*)d_in[6];
    const float* vw  = (const float*)d_in[7];
    const float* ow  = (const float*)d_in[8];

    float* out   = (float*)d_out;
    float* outd  = out;                    // attn_output_d [T,B,E]
    float* attnd = out + 1*(size_t)NBHTD;  // attn_d [B,T,S]
    float* outs  = out + 2*(size_t)NBHTD;  // attn_output_s
    float* attns = out + 3*(size_t)NBHTD;  // attn_s

    // ---- ws layout (exactly 128 MiB = 8*NBHTD ushorts) ----
    unsigned short* ws_u16 = (unsigned short*)d_ws;
    unsigned short* Khi  = ws_u16;                     // R1: 4*NBHTD u16
    unsigned short* Klo  = Khi  + (size_t)NBHTD;
    unsigned short* Vthi = Klo  + (size_t)NBHTD;
    unsigned short* Vtlo = Vthi + (size_t)NBHTD;
    unsigned short* R2a  = Vtlo + (size_t)NBHTD;       // 2*NBHTD u16 (33.5 MB)
    unsigned short* R2b  = R2a  + 2*(size_t)NBHTD;     // 2*NBHTD u16

    // phase-1 overlays of R2a: weight splits (qw,kw,vw)
    const size_t EE = (size_t)E_DIM*E_DIM;
    unsigned short* qwhi = R2a;
    unsigned short* qwlo = qwhi + EE;
    unsigned short* kwhi = qwlo + EE;
    unsigned short* kwlo = kwhi + EE;
    unsigned short* vwhi = kwlo + EE;
    unsigned short* vwlo = vwhi + EE;
    // phase-2/3 overlay of R2a: o_s fp32
    float* Osb = (float*)R2a;
    // phase-4 overlay of R2a: o_d split
    unsigned short* Odhi = R2a;
    unsigned short* Odlo = Odhi + (size_t)NBHTD;
    // R2b: o_s split (attn#1 -> outproj)
    unsigned short* Oshi = R2b;
    unsigned short* Oslo = Oshi + (size_t)NBHTD;
    // phase-5 overlay of R1 (K/V splits dead): ow split
    unsigned short* owhi = ws_u16;
    unsigned short* owlo = owhi + EE;

    // d_out borrowing:
    float* Q1h = outd;    // fp32 [B,H,T,D], dead before outproj writes outd
    float* Q2h = outs;    // dead before outproj writes outs
    float* Vh  = attnd;   // fp32 V, dead before attn#2 writes attnd
    unsigned short* Ahi = (unsigned short*)attns;   // A-split arena (phase 1)
    unsigned short* Alo = Ahi + (size_t)NBHTD;      // dead before attn#1 writes attns

    const dim3 ggrid(8, 64);

    // ---- phase 1: projections (bf16x3 MFMA) ----
    split_pair<<<512, 256, 0, stream>>>(qw, qwhi, qwlo, 1.f);
    split_pair<<<512, 256, 0, stream>>>(kw, kwhi, kwlo, 1.f);
    split_pair<<<512, 256, 0, stream>>>(vw, vwhi, vwlo, 1.f);

    split_pair<<<4096, 256, 0, stream>>>(key, Ahi, Alo, 1.f);
    gemm_bf3<0,1><<<ggrid, 256, 0, stream>>>(Ahi, Alo, kwhi, kwlo, nullptr, Khi, Klo);

    split_pair<<<4096, 256, 0, stream>>>(val, Ahi, Alo, 1.f);
    gemm_bf3<0,0><<<ggrid, 256, 0, stream>>>(Ahi, Alo, vwhi, vwlo, Vh, nullptr, nullptr);
    split_vt<<<dim3(16, 128), 256, 0, stream>>>(Vh, Vthi, Vtlo);

    split_pair<<<4096, 256, 0, stream>>>(q1, Ahi, Alo, 0.125f);
    gemm_bf3<0,0><<<ggrid, 256, 0, stream>>>(Ahi, Alo, qwhi, qwlo, Q1h, nullptr, nullptr);

    split_pair<<<4096, 256, 0, stream>>>(q2, Ahi, Alo, 0.125f);
    gemm_bf3<0,0><<<ggrid, 256, 0, stream>>>(Ahi, Alo, qwhi, qwlo, Q2h, nullptr, nullptr);

    // ---- phase 2: stream s ----
    attn_mfma<<<dim3(512), 256, 0, stream>>>(Q2h, Khi, Klo, Vthi, Vtlo,
                                             Osb, Oshi, Oslo, attns);

    // ---- phase 3: k/v update ----
    add_k<<<4096, 256, 0, stream>>>(Khi, Klo, Osb);
    add_v<<<8192, 256, 0, stream>>>(Vh, Osb);
    split_vt<<<dim3(16, 128), 256, 0, stream>>>(Vh, Vthi, Vtlo);

    // ---- phase 4: stream d ----
    attn_mfma<<<dim3(512), 256, 0, stream>>>(Q1h, Khi, Klo, Vthi, Vtlo,
                                             nullptr, Odhi, Odlo, attnd);

    // ---- phase 5: output projections ----
    split_pair<<<512, 256, 0, stream>>>(ow, owhi, owlo, 1.f);
    gemm_bf3<1,2><<<ggrid, 256, 0, stream>>>(Oshi, Oslo, owhi, owlo, outs, nullptr, nullptr);
    gemm_bf3<1,2><<<ggrid, 256, 0, stream>>>(Odhi, Odlo, owhi, owlo, outd, nullptr, nullptr);
}